// Round 1
// baseline (161.538 us; speedup 1.0000x reference)
//
#include <hip/hip_runtime.h>
#include <math.h>

#ifndef M_PI
#define M_PI 3.14159265358979323846
#endif

#define DMODEL 256
#define NSTATE 64
#define LSEQ   8192
#define LOG2L  13

// Workspace layout (bytes). Total ~16.7 MB.
#define OFF_KPRM 0                                 // float4[LSEQ]: w_re, w_im, t_re, t_im
#define OFF_TW   (OFF_KPRM + LSEQ*16)              // float2[LSEQ/2]: ifft twiddles e^{+2pi i j/L}
#define OFF_CDT  (OFF_TW + (LSEQ/2)*8)             // float[DMODEL]: 2/dt
#define OFF_DN   (OFF_CDT + 1024)                  // float4[2*DMODEL*NSTATE]: {lam_re,lam_im,w1r,w1i},{w2,w3,0,0}
#define OFF_KHAT (OFF_DN + DMODEL*NSTATE*32)       // float2[DMODEL*LSEQ]

// ---------------------------------------------------------------- precompute
__global__ __launch_bounds__(256) void precompute_kernel(
    const float* __restrict__ Lre, const float* __restrict__ Lim,
    const float* __restrict__ Pre, const float* __restrict__ Pim,
    const float* __restrict__ Bre, const float* __restrict__ Bim,
    const float* __restrict__ log_dt, char* __restrict__ ws)
{
  const int t = blockIdx.x * blockDim.x + threadIdx.x;  // 0..16383
  float4* kprm = (float4*)(ws + OFF_KPRM);
  float2* tw   = (float2*)(ws + OFF_TW);
  float*  cdt  = (float*)(ws + OFF_CDT);
  float4* dn   = (float4*)(ws + OFF_DN);

  if (t < LSEQ) {
    // z_k = exp(-2pi i k / L) in double; denom = 1+z with reference's eps clamp
    double th = (-2.0 * M_PI / (double)LSEQ) * (double)t;
    double s, c;
    sincos(th, &s, &c);
    double zr = c, zi = s;
    double dr = 1.0 + zr, di = zi;
    const double eps = 1.1920928955078125e-7;  // FLT_EPSILON
    if (sqrt(dr*dr + di*di) < eps) { dr = eps; di = 0.0; }
    double inv = 1.0 / (dr*dr + di*di);
    double ur = 1.0 - zr, ui = -zi;
    double wr = (ur*dr + ui*di) * inv;   // (1-z)/(1+z)
    double wi = (ui*dr - ur*di) * inv;
    double tr =  2.0*dr*inv;             // 2/(1+z)
    double ti = -2.0*di*inv;
    kprm[t] = make_float4((float)wr, (float)wi, (float)tr, (float)ti);
  }
  if (t < LSEQ/2) {
    // inverse-FFT twiddles e^{+2pi i j / L}
    double th = (2.0 * M_PI / (double)LSEQ) * (double)t;
    double s, c; sincos(th, &s, &c);
    tw[t] = make_float2((float)c, (float)s);
  }
  if (t < DMODEL*NSTATE) {
    float lre = Lre[t], lim = Lim[t];
    float pre = Pre[t], pim = Pim[t];
    float bre = Bre[t], bim = Bim[t];
    // Lam = -softplus(Lre) + i*Lim
    float sp = fmaxf(lre, 0.0f) + log1pf(expf(-fabsf(lre)));
    // conj(P)*B (complex), |P|^2, |B|^2 (real); conj(B)*P = conj(conj(P)*B)
    float w1r = pre*bre + pim*bim;
    float w1i = pre*bim - pim*bre;
    float w2  = pre*pre + pim*pim;
    float w3  = bre*bre + bim*bim;
    dn[2*t]   = make_float4(-sp, lim, w1r, w1i);
    dn[2*t+1] = make_float4(w2, w3, 0.0f, 0.0f);
  }
  if (t < DMODEL) {
    cdt[t] = 2.0f * expf(-log_dt[t]);   // 2/dt
  }
}

// ---------------------------------------------------------------- cauchy + woodbury
__global__ __launch_bounds__(256) void cauchy_kernel(char* __restrict__ ws)
{
  const int k = blockIdx.x * 256 + threadIdx.x;   // 0..8191
  const int d = blockIdx.y;                       // 0..255
  const float4* kprm = (const float4*)(ws + OFF_KPRM);
  const float*  cdt  = (const float*)(ws + OFF_CDT);
  const float4* dn   = (const float4*)(ws + OFF_DN) + (size_t)d * (2*NSTATE);
  float2* khat = (float2*)(ws + OFF_KHAT);

  const float4 kp = kprm[k];
  const float c = cdt[d];                         // wave-uniform
  const float gre = c * kp.x, gim = c * kp.y;     // g = (2/dt)*(1-z)/(1+z)

  float PRBr=0.f, PRBi=0.f, BRPr=0.f, BRPi=0.f;
  float PRPr=0.f, PRPi=0.f, BRBr=0.f, BRBi=0.f;

#pragma unroll 8
  for (int n = 0; n < NSTATE; ++n) {
    // wave-uniform loads -> scalar cache
    float4 a = dn[2*n];        // lam_re, lam_im, w1r, w1i
    float4 b = dn[2*n+1];      // w2, w3, -, -
    float dre = gre - a.x;
    float dim = gim - a.y;
    float inv = __builtin_amdgcn_rcpf(fmaf(dre, dre, dim*dim));
    float rr =  dre * inv;     // r = 1/(g - lam)
    float ri = -dim * inv;
    PRBr = fmaf(a.z, rr, fmaf(-a.w, ri, PRBr));   // += w1 * r
    PRBi = fmaf(a.z, ri, fmaf( a.w, rr, PRBi));
    BRPr = fmaf(a.z, rr, fmaf( a.w, ri, BRPr));   // += conj(w1) * r
    BRPi = fmaf(a.z, ri, fmaf(-a.w, rr, BRPi));
    PRPr = fmaf(b.x, rr, PRPr);                   // += |P|^2 * r
    PRPi = fmaf(b.x, ri, PRPi);
    BRBr = fmaf(b.y, rr, BRBr);                   // += |B|^2 * r
    BRBi = fmaf(b.y, ri, BRBi);
  }

  // K_hat = (2/(1+z)) * (BRB - BRP*PRB/(1+PRP))
  float denr = 1.0f + PRPr, deni = PRPi;
  float numr = BRPr*PRBr - BRPi*PRBi;
  float numi = BRPr*PRBi + BRPi*PRBr;
  float inv2 = 1.0f / fmaf(denr, denr, deni*deni);
  float qr = fmaf(numr, denr,  numi*deni) * inv2;
  float qi = fmaf(numi, denr, -numr*deni) * inv2;
  float vr = BRBr - qr, vi = BRBi - qi;
  float khr = kp.z*vr - kp.w*vi;
  float khi = kp.z*vi + kp.w*vr;
  khat[(size_t)d * LSEQ + k] = make_float2(khr, khi);
}

// ---------------------------------------------------------------- ifft (radix-2 DIT in LDS), Re() out
__global__ __launch_bounds__(512) void ifft_kernel(const char* __restrict__ ws,
                                                   const float* __restrict__ Din,
                                                   float* __restrict__ out)
{
  __shared__ float re[LSEQ];
  __shared__ float im[LSEQ];
  const int d = blockIdx.x;
  const int t = threadIdx.x;     // 0..511
  const float2* row = (const float2*)(ws + OFF_KHAT) + (size_t)d * LSEQ;
  const float2* tw  = (const float2*)(ws + OFF_TW);

  // bit-reversed gather from global (L2-resident), linear LDS store
  for (int i = t; i < LSEQ; i += 512) {
    int r = (int)(__brev((unsigned)i) >> (32 - LOG2L));
    float2 v = row[r];
    re[i] = v.x; im[i] = v.y;
  }
  __syncthreads();

  for (int s = 1; s <= LOG2L; ++s) {
    const int h = 1 << (s - 1);
    const int tshift = LOG2L - s;
    for (int b = t; b < (LSEQ/2); b += 512) {
      const int pos = b & (h - 1);
      const int grp = b >> (s - 1);
      const int i0 = (grp << s) + pos;
      const int i1 = i0 + h;
      const float2 w = tw[pos << tshift];         // e^{+2pi i pos / 2^s}
      float x1r = re[i1], x1i = im[i1];
      float t1r = x1r*w.x - x1i*w.y;
      float t1i = x1r*w.y + x1i*w.x;
      float x0r = re[i0], x0i = im[i0];
      re[i0] = x0r + t1r; im[i0] = x0i + t1i;
      re[i1] = x0r - t1r; im[i1] = x0i - t1i;
    }
    __syncthreads();
  }

  const float scale = 1.0f / (float)LSEQ;
  float* orow = out + (size_t)d * LSEQ;
  for (int i = t; i < LSEQ; i += 512) orow[i] = re[i] * scale;

  // second tuple output: D passthrough (zeros buffer)
  if (d == 0 && t < DMODEL) out[(size_t)DMODEL * LSEQ + t] = Din[t];
}

// ---------------------------------------------------------------- launch
extern "C" void kernel_launch(void* const* d_in, const int* in_sizes, int n_in,
                              void* d_out, int out_size, void* d_ws, size_t ws_size,
                              hipStream_t stream)
{
  const float* Lre    = (const float*)d_in[0];
  const float* Lim    = (const float*)d_in[1];
  const float* Pre    = (const float*)d_in[2];
  const float* Pim    = (const float*)d_in[3];
  const float* Bre    = (const float*)d_in[4];
  const float* Bim    = (const float*)d_in[5];
  const float* log_dt = (const float*)d_in[6];
  const float* Din    = (const float*)d_in[7];
  float* out = (float*)d_out;
  char* ws = (char*)d_ws;

  hipLaunchKernelGGL(precompute_kernel, dim3(64), dim3(256), 0, stream,
                     Lre, Lim, Pre, Pim, Bre, Bim, log_dt, ws);
  hipLaunchKernelGGL(cauchy_kernel, dim3(LSEQ/256, DMODEL), dim3(256), 0, stream, ws);
  hipLaunchKernelGGL(ifft_kernel, dim3(DMODEL), dim3(512), 0, stream, ws, Din, out);
}

// Round 2
// 123.941 us; speedup vs baseline: 1.3033x; 1.3033x over previous
//
#include <hip/hip_runtime.h>
#include <math.h>

#ifndef M_PI
#define M_PI 3.14159265358979323846
#endif

#define DMODEL 256
#define NSTATE 64
#define LSEQ   8192
#define INVL   (1.0f/8192.0f)

// Workspace layout (bytes). Total ~561 KB.
#define OFF_TW  0                                  // float2[6144]: e^{+2pi i j/L}, j<3L/4
#define OFF_DN  (6144*8)                           // float4[2*DMODEL*NSTATE]
#define OFF_CDT (OFF_DN + DMODEL*NSTATE*32)        // float[DMODEL]: 2/dt

__device__ __forceinline__ float sin_rev(float r) {
#if __has_builtin(__builtin_amdgcn_sinf)
  return __builtin_amdgcn_sinf(r);        // D = sin(S0 * 2pi), input in revolutions
#else
  return __sinf(r * 6.283185307179586f);
#endif
}
__device__ __forceinline__ float cos_rev(float r) {
#if __has_builtin(__builtin_amdgcn_cosf)
  return __builtin_amdgcn_cosf(r);
#else
  return __cosf(r * 6.283185307179586f);
#endif
}

__device__ __forceinline__ float2 cmul(float2 a, float2 b) {
  return make_float2(a.x*b.x - a.y*b.y, a.x*b.y + a.y*b.x);
}

// K_hat/L from the 4 complex sums. PRB*BRP = (S1+iS2)(S1-iS2) = S1^2 + S2^2.
// Prefactor 2/(1+z) = 1 + i*T; fold 1/L here.
__device__ __forceinline__ float2 woodbury(float2 S1, float2 S2, float2 S3,
                                           float2 S4, float T) {
  float nr = (S1.x*S1.x - S1.y*S1.y) + (S2.x*S2.x - S2.y*S2.y);
  float ni = 2.0f*(S1.x*S1.y + S2.x*S2.y);
  float dr = 1.0f + S3.x, di = S3.y;
  float inv = __builtin_amdgcn_rcpf(fmaf(dr, dr, di*di));
  float qr = (nr*dr + ni*di) * inv;
  float qi = (ni*dr - nr*di) * inv;
  float vr = S4.x - qr, vi = S4.y - qi;
  return make_float2((vr - T*vi)*INVL, (vi + T*vr)*INVL);
}

// ---------------------------------------------------------------- precompute
__global__ __launch_bounds__(256) void precompute_kernel(
    const float* __restrict__ Lre, const float* __restrict__ Lim,
    const float* __restrict__ Pre, const float* __restrict__ Pim,
    const float* __restrict__ Bre, const float* __restrict__ Bim,
    const float* __restrict__ log_dt, char* __restrict__ ws)
{
  const int t = blockIdx.x * blockDim.x + threadIdx.x;  // 0..16383
  float2* tw  = (float2*)(ws + OFF_TW);
  float4* dn  = (float4*)(ws + OFF_DN);
  float*  cdt = (float*)(ws + OFF_CDT);

  if (t < 6144) {
    double th = (2.0 * M_PI / (double)LSEQ) * (double)t;
    double s, c; sincos(th, &s, &c);
    tw[t] = make_float2((float)c, (float)s);
  }
  {
    float lre = Lre[t], lim = Lim[t];
    float pre = Pre[t], pim = Pim[t];
    float bre = Bre[t], bim = Bim[t];
    float sp = fmaxf(lre, 0.0f) + log1pf(expf(-fabsf(lre)));  // softplus
    float w1r = pre*bre + pim*bim;   // Re conj(P)*B
    float w1i = pre*bim - pim*bre;   // Im conj(P)*B
    float w2  = pre*pre + pim*pim;   // |P|^2
    float w3  = bre*bre + bim*bim;   // |B|^2
    dn[2*t]   = make_float4(lim, sp, sp*sp, w1r);
    dn[2*t+1] = make_float4(w1i, w2, w3, 0.0f);
  }
  if (t < DMODEL) cdt[t] = 2.0f * expf(-log_dt[t]);
}

// ---------------------------------------------------------------- fused cauchy + ifft
// One block per d. Phase 1: K_hat evaluated directly at digit-reversed LDS
// positions with the radix-2 first stage folded in. Phase 2: 6 radix-4 DIT
// stages in LDS (inverse transform, W = e^{+2pi i/L}). Output natural order.
__global__ __launch_bounds__(1024) void fused_kernel(
    const float4* __restrict__ dn_all, const float* __restrict__ cdt,
    const float2* __restrict__ tw, const float* __restrict__ Din,
    float* __restrict__ out)
{
  __shared__ __align__(16) float2 xy[LSEQ];   // 64 KB
  const int d = blockIdx.x;
  const int t = threadIdx.x;                  // 0..1023
  const float4* dn = dn_all + (size_t)d * (2*NSTATE);
  const float c = cdt[d];                     // 2/dt, wave-uniform

  // ---- Phase 1: cauchy rows, digit-reversed placement, radix-2 folded in.
  // Position pair (2b, 2b+1) sources k = sigma(2b) and k + 4096.
  for (int it = 0; it < 4; ++it) {
    const int b = t + (it << 10);             // 0..4095
    const unsigned p = (unsigned)(2*b);
    const unsigned r = __brev(p) >> 19;       // 13-bit reversal
    const int kA = (int)((r & 0x1000u) | ((r & 0x0555u) << 1) | ((r & 0x0AAAu) >> 1));
    // kA < 4096. T = tan(pi k / L); (1-z)/(1+z) = i*T exactly (no cancellation).
    const float rev = (float)kA * (1.0f/16384.0f);
    const float sA = sin_rev(rev), cAc = cos_rev(rev);
    float TA = sA * __builtin_amdgcn_rcpf(cAc);
    float TB = -cAc * __builtin_amdgcn_rcpf(sA);    // tan(x + pi/2) = -cot(x)
    TA = fminf(fmaxf(TA, -1e7f), 1e7f);
    TB = fminf(fmaxf(TB, -1e7f), 1e7f);
    const float gA = c * TA, gB = c * TB;     // g = i*gIm, purely imaginary

    float2 S1a = {0,0}, S2a = {0,0}, S3a = {0,0}, S4a = {0,0};
    float2 S1b = {0,0}, S2b = {0,0}, S3b = {0,0}, S4b = {0,0};
#pragma unroll 8
    for (int n = 0; n < NSTATE; ++n) {
      const float4 a = dn[2*n];       // lam_im, sp, sp^2, w1r   (wave-uniform -> s_load)
      const float4 w = dn[2*n+1];     // w1i, |P|^2, |B|^2, 0
      {
        const float dim = gA - a.x;
        const float inv = __builtin_amdgcn_rcpf(fmaf(dim, dim, a.z));
        const float rr = a.y * inv;   // Re 1/(g-Lam) ; Im = -di
        const float di = dim * inv;
        S1a.x = fmaf(a.w, rr, S1a.x);  S1a.y = fmaf(a.w, -di, S1a.y);
        S2a.x = fmaf(w.x, rr, S2a.x);  S2a.y = fmaf(w.x, -di, S2a.y);
        S3a.x = fmaf(w.y, rr, S3a.x);  S3a.y = fmaf(w.y, -di, S3a.y);
        S4a.x = fmaf(w.z, rr, S4a.x);  S4a.y = fmaf(w.z, -di, S4a.y);
      }
      {
        const float dim = gB - a.x;
        const float inv = __builtin_amdgcn_rcpf(fmaf(dim, dim, a.z));
        const float rr = a.y * inv;
        const float di = dim * inv;
        S1b.x = fmaf(a.w, rr, S1b.x);  S1b.y = fmaf(a.w, -di, S1b.y);
        S2b.x = fmaf(w.x, rr, S2b.x);  S2b.y = fmaf(w.x, -di, S2b.y);
        S3b.x = fmaf(w.y, rr, S3b.x);  S3b.y = fmaf(w.y, -di, S3b.y);
        S4b.x = fmaf(w.z, rr, S4b.x);  S4b.y = fmaf(w.z, -di, S4b.y);
      }
    }
    const float2 KA = woodbury(S1a, S2a, S3a, S4a, TA);
    const float2 KB = woodbury(S1b, S2b, S3b, S4b, TB);
    // radix-2 first stage: sum at 2b, diff at 2b+1 (16B store, conflict-free)
    ((float4*)xy)[b] = make_float4(KA.x + KB.x, KA.y + KB.y,
                                   KA.x - KB.x, KA.y - KB.y);
  }
  __syncthreads();

  // ---- Phase 2: six radix-4 DIT stages, spans h = 2,8,32,128,512,2048.
#pragma unroll
  for (int s = 0; s < 6; ++s) {
    const int h = 2 << (2*s);
    const int twsh = 10 - 2*s;                // tw stride = L/(4h) = 1024>>2s
#pragma unroll
    for (int j = 0; j < 2; ++j) {
      const int bb = t + (j << 10);           // butterfly id 0..2047
      const int pos = bb & (h - 1);
      const int i0 = ((bb >> (1 + 2*s)) << (3 + 2*s)) + pos;
      const int ti = pos << twsh;
      const float2 w1 = tw[ti];
      const float2 w2 = tw[2*ti];
      const float2 w3 = tw[3*ti];
      const float2 x0 = xy[i0];
      const float2 x1 = xy[i0 + h];
      const float2 x2 = xy[i0 + 2*h];
      const float2 x3 = xy[i0 + 3*h];
      const float2 t1 = cmul(w1, x1);
      const float2 t2 = cmul(w2, x2);
      const float2 t3 = cmul(w3, x3);
      const float2 u0 = make_float2(x0.x + t2.x, x0.y + t2.y);
      const float2 u1 = make_float2(x0.x - t2.x, x0.y - t2.y);
      const float2 u2 = make_float2(t1.x + t3.x, t1.y + t3.y);
      const float2 vv = make_float2(t1.x - t3.x, t1.y - t3.y);
      xy[i0]         = make_float2(u0.x + u2.x, u0.y + u2.y);   // Y0
      xy[i0 + h]     = make_float2(u1.x - vv.y, u1.y + vv.x);   // Y1 = u1 + i*vv
      xy[i0 + 2*h]   = make_float2(u0.x - u2.x, u0.y - u2.y);   // Y2
      xy[i0 + 3*h]   = make_float2(u1.x + vv.y, u1.y - vv.x);   // Y3 = u1 - i*vv
    }
    __syncthreads();
  }

  // ---- Store real part (already scaled by 1/L), natural order, coalesced.
  float* orow = out + (size_t)d * LSEQ;
  for (int i = t; i < LSEQ; i += 1024) orow[i] = xy[i].x;

  // second tuple output: D passthrough (zeros buffer)
  if (d == 0 && t < DMODEL) out[(size_t)DMODEL * LSEQ + t] = Din[t];
}

// ---------------------------------------------------------------- launch
extern "C" void kernel_launch(void* const* d_in, const int* in_sizes, int n_in,
                              void* d_out, int out_size, void* d_ws, size_t ws_size,
                              hipStream_t stream)
{
  const float* Lre    = (const float*)d_in[0];
  const float* Lim    = (const float*)d_in[1];
  const float* Pre    = (const float*)d_in[2];
  const float* Pim    = (const float*)d_in[3];
  const float* Bre    = (const float*)d_in[4];
  const float* Bim    = (const float*)d_in[5];
  const float* log_dt = (const float*)d_in[6];
  const float* Din    = (const float*)d_in[7];
  float* out = (float*)d_out;
  char* ws = (char*)d_ws;

  hipLaunchKernelGGL(precompute_kernel, dim3(64), dim3(256), 0, stream,
                     Lre, Lim, Pre, Pim, Bre, Bim, log_dt, ws);
  hipLaunchKernelGGL(fused_kernel, dim3(DMODEL), dim3(1024), 0, stream,
                     (const float4*)(ws + OFF_DN), (const float*)(ws + OFF_CDT),
                     (const float2*)(ws + OFF_TW), Din, out);
}